// Round 1
// baseline (33.180 us; speedup 1.0000x reference)
//
#include <hip/hip_runtime.h>

#define KDIM 16
#define NSPIRAL 81

// spiral_pattern(4,4) flattened row-major (index c = y*9+x), values 1..81
__device__ __constant__ int d_spiral[NSPIRAL] = {
 74,73,72,71,70,69,68,67,66,
 75,44,43,42,41,40,39,38,65,
 76,45,22,21,20,19,18,37,64,
 77,46,23, 8, 7, 6,17,36,63,
 78,47,24, 9, 1, 5,16,35,62,
 79,48,25, 2, 3, 4,15,34,61,
 80,49,10,11,12,13,14,33,60,
 81,26,27,28,29,30,31,32,59,
 50,51,52,53,54,55,56,57,58
};

__global__ __launch_bounds__(256) void calc_vector_kernel(
    const float* __restrict__ windows,
    const float* __restrict__ templates,
    float* __restrict__ out,
    int npix, int C)
{
    __shared__ int s_spiral[NSPIRAL];
    const int tid = threadIdx.x;
    if (tid < NSPIRAL) s_spiral[tid] = d_spiral[tid];
    __syncthreads();

    const int wave = tid >> 6;
    const int lane = tid & 63;
    const int pix = blockIdx.x * 4 + wave;
    if (pix >= npix) return;

    const int rowlen = C * KDIM;              // 1312 floats
    const int nf4 = rowlen >> 2;              // 328 float4s
    const float* wrow = windows + (size_t)pix * rowlen;

    // each lane owns k-segment (lane&3)*4 .. +3 of the template
    const int kseg = (lane & 3) * 4;
    const float4 t4 = *reinterpret_cast<const float4*>(templates + (size_t)pix * KDIM + kseg);

    int bestkey = 0x7FFFFFFF;
    int cost81 = 0;

    #pragma unroll
    for (int it = 0; it < 6; ++it) {
        const int f = it * 64 + lane;         // float4 index within row
        const int c = it * 16 + (lane >> 2);  // candidate this 4-lane group covers
        float s = 0.0f;
        if (f < nf4) {
            const float4 w4 = *reinterpret_cast<const float4*>(wrow + f * 4);
            s = fabsf(w4.x - t4.x) + fabsf(w4.y - t4.y) +
                fabsf(w4.z - t4.z) + fabsf(w4.w - t4.w);
        }
        // sum the 4 lanes of the group -> full 16-wide SAD on every lane
        s += __shfl_xor(s, 1);
        s += __shfl_xor(s, 2);
        const int cost = (int)s;              // exact integer <= 4080
        if (f < nf4 && c < NSPIRAL) {
            const int n = s_spiral[c];
            const int key = (cost << 14) | (n << 7) | c;
            bestkey = min(bestkey, key);
        }
        if (c == NSPIRAL && f < nf4) cost81 = cost;  // lanes 4..7 at it==5
    }

    // wave-wide min reduce of the packed key
    #pragma unroll
    for (int off = 32; off >= 1; off >>= 1)
        bestkey = min(bestkey, __shfl_xor(bestkey, off));
    cost81 = __shfl(cost81, 4);

    const int idx_bm      = bestkey & 127;
    const int min_cost_bm = bestkey >> 14;
    const bool mv_mask    = cost81 < min_cost_bm;
    const int min_idx     = mv_mask ? NSPIRAL : idx_bm;
    const int mcv         = min(cost81, min_cost_bm);

    // output layout: [vec: npix*2][tmpl: npix*16][mask: npix][cost: npix]
    float* out_vec  = out;
    float* out_tmpl = out + (size_t)npix * 2;
    float* out_mask = out + (size_t)npix * 18;
    float* out_cost = out + (size_t)npix * 19;

    if (lane < 4) {
        const float4 w4 = *reinterpret_cast<const float4*>(wrow + min_idx * KDIM + lane * 4);
        *reinterpret_cast<float4*>(out_tmpl + (size_t)pix * KDIM + lane * 4) = w4;
    }
    if (lane == 0) {
        out_vec[(size_t)pix * 2 + 0] = (float)(4 - idx_bm / 9);
        out_vec[(size_t)pix * 2 + 1] = (float)(4 - idx_bm % 9);
        out_mask[pix] = mv_mask ? 1.0f : 0.0f;
        out_cost[pix] = (float)mcv;
    }
}

extern "C" void kernel_launch(void* const* d_in, const int* in_sizes, int n_in,
                              void* d_out, int out_size, void* d_ws, size_t ws_size,
                              hipStream_t stream) {
    const float* windows   = (const float*)d_in[0];
    const float* templates = (const float*)d_in[1];
    float* out = (float*)d_out;

    const int npix = in_sizes[1] / KDIM;          // B*H*W = 32400
    const int C    = in_sizes[0] / in_sizes[1];   // 82

    const int blocks = (npix + 3) / 4;            // 4 waves (pixels) per block
    calc_vector_kernel<<<blocks, 256, 0, stream>>>(windows, templates, out, npix, C);
}

// Round 2
// 32.388 us; speedup vs baseline: 1.0245x; 1.0245x over previous
//
#include <hip/hip_runtime.h>

#define KDIM 16
#define NSPIRAL 81

typedef float f4 __attribute__((ext_vector_type(4)));

// spiral_pattern(4,4) flattened row-major (index c = y*9+x), values 1..81
__device__ __constant__ int d_spiral[NSPIRAL] = {
 74,73,72,71,70,69,68,67,66,
 75,44,43,42,41,40,39,38,65,
 76,45,22,21,20,19,18,37,64,
 77,46,23, 8, 7, 6,17,36,63,
 78,47,24, 9, 1, 5,16,35,62,
 79,48,25, 2, 3, 4,15,34,61,
 80,49,10,11,12,13,14,33,60,
 81,26,27,28,29,30,31,32,59,
 50,51,52,53,54,55,56,57,58
};

// C_CONST > 0: compile-time candidate count (fast path, guards fold).
// C_CONST < 0: generic runtime path.
template<int C_CONST>
__global__ __launch_bounds__(256) void calc_vector_kernel(
    const float* __restrict__ windows,
    const float* __restrict__ templates,
    float* __restrict__ out,
    int npix, int C_rt)
{
    __shared__ int s_spiral[NSPIRAL];
    const int tid = threadIdx.x;
    if (tid < NSPIRAL) s_spiral[tid] = d_spiral[tid];
    __syncthreads();

    const int C   = (C_CONST > 0) ? C_CONST : C_rt;
    const int wave = tid >> 6;
    const int lane = tid & 63;
    const int pix = blockIdx.x * 4 + wave;
    if (pix >= npix) return;

    const int rowlen = C * KDIM;              // 1312 floats
    const int nf4 = rowlen >> 2;              // 328 float4s
    const float* wrow = windows + (size_t)pix * rowlen;

    // each lane owns k-segment (lane&3)*4 .. +3 of the template
    const int kseg = (lane & 3) * 4;
    const f4 t4 = __builtin_nontemporal_load(
        reinterpret_cast<const f4*>(templates + (size_t)pix * KDIM + kseg));

    int bestkey = 0x7FFFFFFF;
    int cost81 = 0;

    #pragma unroll
    for (int it = 0; it < 6; ++it) {
        const int f = it * 64 + lane;         // float4 index within row
        const int c = it * 16 + (lane >> 2);  // candidate this 4-lane group covers
        // compile-time-foldable activity guard on the fast path
        const bool active = (C_CONST > 0) ? (it < (nf4 >> 6) || (f < nf4))
                                          : (f < nf4);
        float s = 0.0f;
        if (active) {
            const f4 w4 = __builtin_nontemporal_load(
                reinterpret_cast<const f4*>(wrow + f * 4));
            s = fabsf(w4.x - t4.x) + fabsf(w4.y - t4.y) +
                fabsf(w4.z - t4.z) + fabsf(w4.w - t4.w);
        }
        // sum the 4 lanes of the group -> full 16-wide SAD on every lane
        s += __shfl_xor(s, 1);
        s += __shfl_xor(s, 2);
        const int cost = (int)s;              // exact integer <= 4080
        if (active && c < NSPIRAL) {
            const int n = s_spiral[c];
            const int key = (cost << 14) | (n << 7) | c;
            bestkey = min(bestkey, key);
        }
        if (active && c == NSPIRAL) cost81 = cost;  // lanes 4..7 at it==5
    }

    // wave-wide min reduce of the packed key
    #pragma unroll
    for (int off = 32; off >= 1; off >>= 1)
        bestkey = min(bestkey, __shfl_xor(bestkey, off));
    cost81 = __shfl(cost81, 4);

    const int idx_bm      = bestkey & 127;
    const int min_cost_bm = bestkey >> 14;
    const bool mv_mask    = cost81 < min_cost_bm;
    const int min_idx     = mv_mask ? NSPIRAL : idx_bm;
    const int mcv         = min(cost81, min_cost_bm);

    // output layout: [vec: npix*2][tmpl: npix*16][mask: npix][cost: npix]
    float* out_vec  = out;
    float* out_tmpl = out + (size_t)npix * 2;
    float* out_mask = out + (size_t)npix * 18;
    float* out_cost = out + (size_t)npix * 19;

    if (lane < 4) {
        const f4 w4 = *reinterpret_cast<const f4*>(wrow + min_idx * KDIM + lane * 4);
        __builtin_nontemporal_store(w4,
            reinterpret_cast<f4*>(out_tmpl + (size_t)pix * KDIM + lane * 4));
    }
    if (lane == 0) {
        out_vec[(size_t)pix * 2 + 0] = (float)(4 - idx_bm / 9);
        out_vec[(size_t)pix * 2 + 1] = (float)(4 - idx_bm % 9);
        out_mask[pix] = mv_mask ? 1.0f : 0.0f;
        out_cost[pix] = (float)mcv;
    }
}

extern "C" void kernel_launch(void* const* d_in, const int* in_sizes, int n_in,
                              void* d_out, int out_size, void* d_ws, size_t ws_size,
                              hipStream_t stream) {
    const float* windows   = (const float*)d_in[0];
    const float* templates = (const float*)d_in[1];
    float* out = (float*)d_out;

    const int npix = in_sizes[1] / KDIM;          // B*H*W = 32400
    const int C    = in_sizes[0] / in_sizes[1];   // 82

    const int blocks = (npix + 3) / 4;            // 4 waves (pixels) per block
    if (C == 82) {
        calc_vector_kernel<82><<<blocks, 256, 0, stream>>>(windows, templates, out, npix, C);
    } else {
        calc_vector_kernel<-1><<<blocks, 256, 0, stream>>>(windows, templates, out, npix, C);
    }
}